// Round 2
// baseline (384.789 us; speedup 1.0000x reference)
//
#include <hip/hip_runtime.h>

#define B_ 4
#define N_ 2048
#define C_ 1024
#define H_ 16
#define D_ 64
#define M_ (B_*N_)      // 8192 rows
#define SCALE_ 0.125f   // HEAD_DIM^-0.5 = 1/8

typedef _Float16 f16;
typedef unsigned short u16;
typedef __attribute__((ext_vector_type(4))) _Float16 f16x4;
typedef __attribute__((ext_vector_type(8))) _Float16 f16x8;
typedef __attribute__((ext_vector_type(4))) float f32x4;

__device__ __forceinline__ f32x4 mfma16(f16x8 a, f16x8 b, f32x4 c) {
  return __builtin_amdgcn_mfma_f32_16x16x32_f16(a, b, c, 0, 0, 0);
}

// ---------------- cast fp32 -> fp16 (RNE) ----------------
__global__ void cast_f32_f16(const float* __restrict__ in, f16* __restrict__ out, int n4) {
  int i = blockIdx.x * blockDim.x + threadIdx.x;
  int stride = gridDim.x * blockDim.x;
  for (; i < n4; i += stride) {
    float4 v = reinterpret_cast<const float4*>(in)[i];
    f16x4 o = { (f16)v.x, (f16)v.y, (f16)v.z, (f16)v.w };
    reinterpret_cast<f16x4*>(out)[i] = o;
  }
}

// ---------------- GEMM: out[m,n] = sum_k A[m,k]*B[n,k]  (B^T form) ----------------
// 128x128 tile, BK=32, 4 waves (2x2), each wave 64x64 (4x4 frags of 16x16x32).
// OUTMODE 0: f16 out.  OUTMODE 1: fp32 out + bias.
template<int OUTMODE>
__global__ __launch_bounds__(256) void gemm_bt(
    const f16* __restrict__ A, const f16* __restrict__ Bm,
    f16* __restrict__ outH, float* __restrict__ outF,
    const float* __restrict__ bias, int M, int Nn, int K)
{
  __shared__ __align__(16) f16 As[128*32];
  __shared__ __align__(16) f16 Bs[128*32];
  const int tid = threadIdx.x;
  const int lane = tid & 63, wid = tid >> 6;
  const int wr = wid >> 1, wc = wid & 1;
  const int g = lane >> 4, r15 = lane & 15;
  const int m0 = blockIdx.y * 128, n0 = blockIdx.x * 128;

  f32x4 acc[4][4] = {};

  for (int k0 = 0; k0 < K; k0 += 32) {
#pragma unroll
    for (int i = 0; i < 2; ++i) {
      int chunk = wid*128 + i*64 + lane;
      int row = chunk >> 2, c8 = (chunk & 3) << 3;
      const f16* ga = A  + (size_t)(m0 + row) * K + k0 + c8;
      const f16* gb = Bm + (size_t)(n0 + row) * K + k0 + c8;
      __builtin_amdgcn_global_load_lds(
        (const __attribute__((address_space(1))) unsigned int*)ga,
        (__attribute__((address_space(3))) unsigned int*)&As[(wid*128 + i*64)*8], 16, 0, 0);
      __builtin_amdgcn_global_load_lds(
        (const __attribute__((address_space(1))) unsigned int*)gb,
        (__attribute__((address_space(3))) unsigned int*)&Bs[(wid*128 + i*64)*8], 16, 0, 0);
    }
    __syncthreads();

    f16x8 af[4], bfr[4];
#pragma unroll
    for (int m = 0; m < 4; ++m)
      af[m] = *reinterpret_cast<const f16x8*>(&As[(wr*64 + m*16 + r15)*32 + g*8]);
#pragma unroll
    for (int n = 0; n < 4; ++n)
      bfr[n] = *reinterpret_cast<const f16x8*>(&Bs[(wc*64 + n*16 + r15)*32 + g*8]);
#pragma unroll
    for (int m = 0; m < 4; ++m)
#pragma unroll
      for (int n = 0; n < 4; ++n)
        acc[m][n] = mfma16(af[m], bfr[n], acc[m][n]);
    __syncthreads();
  }

  // epilogue: C/D layout col=lane&15, row=(lane>>4)*4+r
#pragma unroll
  for (int m = 0; m < 4; ++m) {
#pragma unroll
    for (int n = 0; n < 4; ++n) {
#pragma unroll
      for (int r = 0; r < 4; ++r) {
        int row = m0 + wr*64 + m*16 + g*4 + r;
        int col = n0 + wc*64 + n*16 + r15;
        if (OUTMODE == 0) {
          outH[(size_t)row * Nn + col] = (f16)acc[m][n][r];
        } else {
          outF[(size_t)row * Nn + col] = acc[m][n][r] + bias[col];
        }
      }
    }
  }
}

// ---------------- flash attention ----------------
// grid: (32 q-tiles, 64 bh).  Block 256 = 4 waves; wave w owns q rows q0+w*16..+15.
// KV tiles of 64 staged in LDS; online softmax fp32; P via per-wave LDS.
__global__ __launch_bounds__(256) void attn_kernel(
    const f16* __restrict__ qkv, f16* __restrict__ attn_out)
{
  __shared__ __align__(16) f16 Ks[64*72];      // K rows [kv][d], pad 8
  __shared__ __align__(16) f16 Vts[64*72];     // V transposed [d][kv], pad 8
  __shared__ __align__(16) f16 Ps[4][16*72];   // per-wave P [q][kv], pad 8
  const int tid = threadIdx.x;
  const int lane = tid & 63, w = tid >> 6;
  const int g = lane >> 4, r15 = lane & 15;
  const int bh = blockIdx.y, b = bh >> 4, h = bh & 15;
  const int q0 = blockIdx.x * 64;
  const int RS = 3 * C_;  // qkv row stride

  // Q A-frags (rows r15 of the wave's 16, k = g*8..+7 within d-chunks 0,32)
  const f16* qrow = qkv + (size_t)(b*N_ + q0 + w*16 + r15) * RS + h*D_;
  f16x8 qf0 = *reinterpret_cast<const f16x8*>(qrow + g*8);
  f16x8 qf1 = *reinterpret_cast<const f16x8*>(qrow + 32 + g*8);

  f32x4 acc[4] = {};                          // out [16q][64d] as 4 dblk frags
  float mrow[4] = {-1e30f, -1e30f, -1e30f, -1e30f};
  float lrow[4] = {0.f, 0.f, 0.f, 0.f};

  const int srow = tid >> 2, sc8 = (tid & 3) << 3;   // staging: row 0..63, col8 0..24
  const f16* kg = qkv + (size_t)(b*N_) * RS + C_   + h*D_;
  const f16* vg = qkv + (size_t)(b*N_) * RS + 2*C_ + h*D_;

  for (int kv0 = 0; kv0 < N_; kv0 += 64) {
    // stage K (row-major) and V (transposed) — BOTH 32-col halves of d
    const f16* krow = kg + (size_t)(kv0 + srow) * RS;
    const f16* vrow = vg + (size_t)(kv0 + srow) * RS;
    f16x8 k0v = *reinterpret_cast<const f16x8*>(krow + sc8);
    f16x8 k1v = *reinterpret_cast<const f16x8*>(krow + sc8 + 32);
    *reinterpret_cast<f16x8*>(&Ks[srow*72 + sc8])      = k0v;
    *reinterpret_cast<f16x8*>(&Ks[srow*72 + sc8 + 32]) = k1v;
    f16x8 v0v = *reinterpret_cast<const f16x8*>(vrow + sc8);
    f16x8 v1v = *reinterpret_cast<const f16x8*>(vrow + sc8 + 32);
#pragma unroll
    for (int j = 0; j < 8; ++j) Vts[(sc8 + j)*72 + srow]      = v0v[j];
#pragma unroll
    for (int j = 0; j < 8; ++j) Vts[(sc8 + 32 + j)*72 + srow] = v1v[j];
    __syncthreads();

    // S = Q K^T for 4 kv16 sub-tiles (K rows loaded with A-pattern give B=K^T)
    f32x4 s[4];
#pragma unroll
    for (int t = 0; t < 4; ++t) {
      f16x8 kf0 = *reinterpret_cast<const f16x8*>(&Ks[(t*16 + r15)*72 + g*8]);
      f16x8 kf1 = *reinterpret_cast<const f16x8*>(&Ks[(t*16 + r15)*72 + 32 + g*8]);
      f32x4 z = {};
      z = mfma16(qf0, kf0, z);
      z = mfma16(qf1, kf1, z);
      s[t] = z;
    }
#pragma unroll
    for (int t = 0; t < 4; ++t)
#pragma unroll
      for (int r = 0; r < 4; ++r) s[t][r] *= SCALE_;

    // row max across the 64 kv cols (4 regs here + 16 lanes of group g)
    float tmax[4];
#pragma unroll
    for (int r = 0; r < 4; ++r)
      tmax[r] = fmaxf(fmaxf(s[0][r], s[1][r]), fmaxf(s[2][r], s[3][r]));
#pragma unroll
    for (int off = 1; off < 16; off <<= 1)
#pragma unroll
      for (int r = 0; r < 4; ++r) tmax[r] = fmaxf(tmax[r], __shfl_xor(tmax[r], off));

    float alpha[4], rsum[4];
#pragma unroll
    for (int r = 0; r < 4; ++r) {
      float mn = fmaxf(mrow[r], tmax[r]);
      alpha[r] = __expf(mrow[r] - mn);
      mrow[r] = mn;
      rsum[r] = 0.f;
    }
    f16 pb[4][4];
#pragma unroll
    for (int t = 0; t < 4; ++t)
#pragma unroll
      for (int r = 0; r < 4; ++r) {
        float p = __expf(s[t][r] - mrow[r]);
        rsum[r] += p;
        pb[t][r] = (f16)p;
      }
#pragma unroll
    for (int off = 1; off < 16; off <<= 1)
#pragma unroll
      for (int r = 0; r < 4; ++r) rsum[r] += __shfl_xor(rsum[r], off);
#pragma unroll
    for (int r = 0; r < 4; ++r) lrow[r] = lrow[r]*alpha[r] + rsum[r];
#pragma unroll
    for (int dblk = 0; dblk < 4; ++dblk)
#pragma unroll
      for (int r = 0; r < 4; ++r) acc[dblk][r] *= alpha[r];

    // write P (rows g*4+r, cols t*16+r15) then read back in A-frag pattern
#pragma unroll
    for (int t = 0; t < 4; ++t)
#pragma unroll
      for (int r = 0; r < 4; ++r)
        Ps[w][(g*4 + r)*72 + t*16 + r15] = pb[t][r];

#pragma unroll
    for (int kc = 0; kc < 2; ++kc) {
      f16x8 pf = *reinterpret_cast<const f16x8*>(&Ps[w][r15*72 + kc*32 + g*8]);
#pragma unroll
      for (int dblk = 0; dblk < 4; ++dblk) {
        f16x8 vf = *reinterpret_cast<const f16x8*>(&Vts[(dblk*16 + r15)*72 + kc*32 + g*8]);
        acc[dblk] = mfma16(pf, vf, acc[dblk]);
      }
    }
    __syncthreads();
  }

  float inv[4];
#pragma unroll
  for (int r = 0; r < 4; ++r) inv[r] = 1.0f / lrow[r];
#pragma unroll
  for (int dblk = 0; dblk < 4; ++dblk)
#pragma unroll
    for (int r = 0; r < 4; ++r)
      attn_out[(size_t)(b*N_ + q0 + w*16 + g*4 + r) * C_ + h*D_ + dblk*16 + r15] =
          (f16)(acc[dblk][r] * inv[r]);
}

// ---------------- launch ----------------
extern "C" void kernel_launch(void* const* d_in, const int* in_sizes, int n_in,
                              void* d_out, int out_size, void* d_ws, size_t ws_size,
                              hipStream_t stream) {
  const float* x      = (const float*)d_in[0];   // [4,2048,1024]
  const float* w_qkv  = (const float*)d_in[1];   // [3072,1024]
  const float* w_proj = (const float*)d_in[2];   // [1024,1024]
  const float* b_proj = (const float*)d_in[3];   // [1024]
  float* out = (float*)d_out;                    // [4,2048,1024]

  char* ws = (char*)d_ws;
  f16* xb     = (f16*)(ws);                       // 16 MiB  (reused as attnb)
  f16* wqkvb  = (f16*)(ws + 16777216);            //  6 MiB
  f16* wprojb = (f16*)(ws + 23068672);            //  2 MiB
  f16* qkvb   = (f16*)(ws + 25165824);            // 48 MiB
  f16* attnb  = xb;                               // alias: xb dead after gemm1

  cast_f32_f16<<<2048, 256, 0, stream>>>(x,      xb,     (M_*C_)/4);
  cast_f32_f16<<<1024, 256, 0, stream>>>(w_qkv,  wqkvb,  (3*C_*C_)/4);
  cast_f32_f16<<<512,  256, 0, stream>>>(w_proj, wprojb, (C_*C_)/4);

  // qkv = x @ w_qkv^T  -> f16 [8192, 3072]
  gemm_bt<0><<<dim3(3*C_/128, M_/128), 256, 0, stream>>>(
      xb, wqkvb, qkvb, nullptr, nullptr, M_, 3*C_, C_);

  // attention -> f16 [8192, 1024]
  attn_kernel<<<dim3(N_/64, B_*H_), 256, 0, stream>>>(qkvb, attnb);

  // out = attn @ w_proj^T + b  -> fp32
  gemm_bt<1><<<dim3(C_/128, M_/128), 256, 0, stream>>>(
      attnb, wprojb, nullptr, out, b_proj, M_, C_, C_);
}